// Round 6
// baseline (82.514 us; speedup 1.0000x reference)
//
#include <hip/hip_runtime.h>
#include <hip/hip_bf16.h>
#include <math.h>

#define ALPHA_ 0.2f
#define N_ 16
#define H_ 32
#define W_ 32
#define T_ 16
#define V_ 64
#define P_ (H_*W_)  // 1024

typedef __bf16 bf16x8 __attribute__((ext_vector_type(8)));
typedef float  f32x4  __attribute__((ext_vector_type(4)));

static __device__ inline bf16x8 zero8() {
    bf16x8 z;
    #pragma unroll
    for (int i = 0; i < 8; ++i) z[i] = (__bf16)0.f;
    return z;
}

static __device__ inline unsigned short bf16bits(float f) {
    __hip_bfloat16 b = __float2bfloat16(f);
    return *reinterpret_cast<unsigned short*>(&b);
}

static __device__ inline __bf16 tobf(float f) {
    unsigned short u = bf16bits(f);
    return *reinterpret_cast<__bf16*>(&u);
}

// ---------------------------------------------------------------------------
// Kernel 1: fused transpose + conv MFMA + Ei/Ej partials.
// grid = 2048 (XCD-grouped), bi -> (b, h, vg). block 256 = 4 waves (w-chunks).
// LDS tile sx[r=3][w=32][th=2][v=16][ti=8] bf16 (48 KB), staged from fp32 X
// with h-edge zero fill. A-frag = one aligned ds_read_b128 (v-stride 16B,
// bank-balanced). B-frags self-gathered from CW (L2-hot, 9 KB).
// k-map: dh = kg>>1 (f01) / 2 (f2), ti = (kg&1)*8 + i  [same as prior rounds].
// Whb stored bf16 as (b, t, p, v); Eih*[b][h][v] partials from fp32 acc.
// ---------------------------------------------------------------------------
__global__ __launch_bounds__(256) void conv_k(const float* __restrict__ X,
                                              const float* __restrict__ CW,
                                              const float* __restrict__ CB,
                                              const float* __restrict__ av,
                                              __hip_bfloat16* __restrict__ Whb,
                                              float* __restrict__ Eihi,
                                              float* __restrict__ Eihj) {
    __shared__ __align__(16) __hip_bfloat16 sx[3*32*2*16*8];  // 49152 B
    __shared__ float sEi[4][16], sEj[4][16];

    int orig = blockIdx.x;
    int bi   = (orig & 7) * 256 + (orig >> 3);   // 8 XCDs x 256 contiguous
    int b    = bi >> 7;
    int rem  = bi & 127;
    int h    = rem >> 2;
    int vg   = rem & 3, vb = vg * 16;

    int tid = threadIdx.x, lane = tid & 63, wc = tid >> 6;
    int lm = lane & 15, kg = lane >> 4;

    // ---- self-computed B fragments (same formulas as old prep_k) ----
    bf16x8 Bf01[3], Bf2[3];
    #pragma unroll
    for (int dw = 0; dw < 3; ++dw) {
        #pragma unroll
        for (int i = 0; i < 8; ++i) {
            int ti = (kg & 1)*8 + i;
            int dh = kg >> 1;
            Bf01[dw][i] = tobf(CW[((dh*3+dw)*16+ti)*16 + lm]);
            Bf2 [dw][i] = (kg < 2) ? tobf(CW[((6+dw)*16+ti)*16 + lm]) : (__bf16)0.f;
        }
    }
    float cb = CB[lm];
    f32x4 acc[8];
    #pragma unroll
    for (int wi = 0; wi < 8; ++wi) acc[wi] = (f32x4){cb, cb, cb, cb};

    // ---- stage X slab -> LDS ----
    // word layout: word = ((r*32+w)*2 + th)*64 + v*4 + tiPair&3
    unsigned* sxw = (unsigned*)sx;
    int v4i = tid & 3, tiP = (tid >> 2) & 7, sub = tid >> 5;
    const float* Xbase = X + (size_t)b*(H_*W_*T_*V_) + (size_t)(2*tiP)*V_ + vb + v4i*4;
    #pragma unroll
    for (int it = 0; it < 12; ++it) {
        int rest = it*8 + sub;        // 0..95 = r*32 + w
        int w = rest & 31, r = rest >> 5;
        int hy = h - 1 + r;
        f32x4 xa = {0.f,0.f,0.f,0.f}, xb = {0.f,0.f,0.f,0.f};
        if ((unsigned)hy < (unsigned)H_) {
            const float* p = Xbase + ((size_t)hy*W_ + w)*(T_*V_);
            xa = *(const f32x4*)(p);
            xb = *(const f32x4*)(p + V_);
        }
        int widx = ((r*32 + w)*2 + (tiP>>2))*64 + v4i*16 + (tiP & 3);
        #pragma unroll
        for (int k2 = 0; k2 < 4; ++k2) {
            unsigned pk = (unsigned)bf16bits(xa[k2]) | ((unsigned)bf16bits(xb[k2]) << 16);
            sxw[widx + k2*4] = pk;
        }
    }
    __syncthreads();

    // ---- MFMA u-loop (A-frags from LDS) ----
    // byte strides: ti 2, v 16, th 256, w 512, r 16384
    const char* sxb = (const char*)sx;
    int off01 = (kg>>1)*16384 + (kg&1)*256 + lm*16;
    int off2  = 2*16384       + (kg&1)*256 + lm*16;

    #pragma unroll
    for (int u = 0; u < 10; ++u) {
        int wxu = wc*8 + u - 1;
        bf16x8 f01 = zero8(), f2 = zero8();
        if ((unsigned)wxu < (unsigned)W_) {
            f01 = *(const bf16x8*)(sxb + off01 + wxu*512);
            f2  = *(const bf16x8*)(sxb + off2  + wxu*512);
        }
        #pragma unroll
        for (int dw = 0; dw < 3; ++dw) {
            int wi = u - dw;                     // compile-time
            if (wi >= 0 && wi < 8) {
                acc[wi] = __builtin_amdgcn_mfma_f32_16x16x32_bf16(f01, Bf01[dw], acc[wi], 0, 0, 0);
                acc[wi] = __builtin_amdgcn_mfma_f32_16x16x32_bf16(f2,  Bf2 [dw], acc[wi], 0, 0, 0);
            }
        }
    }

    // ---- fused Ei/Ej partials (lane holds t=lm, v=vb+kg*4+r) ----
    float si[4] = {0.f,0.f,0.f,0.f}, sj[4] = {0.f,0.f,0.f,0.f};
    {
        const float* avb = av + (h & 1)*1024 + wc*8*16 + lm;
        #pragma unroll
        for (int wi = 0; wi < 8; ++wi) {
            float ai = avb[wi*16];
            float aj = avb[wi*16 + 512];
            #pragma unroll
            for (int r = 0; r < 4; ++r) {
                si[r] += acc[wi][r] * ai;
                sj[r] += acc[wi][r] * aj;
            }
        }
        #pragma unroll
        for (int off = 1; off < 16; off <<= 1) {
            #pragma unroll
            for (int r = 0; r < 4; ++r) {
                si[r] += __shfl_xor(si[r], off);
                sj[r] += __shfl_xor(sj[r], off);
            }
        }
    }
    if (lm == 0) {
        #pragma unroll
        for (int r = 0; r < 4; ++r) {
            sEi[wc][kg*4 + r] = si[r];
            sEj[wc][kg*4 + r] = sj[r];
        }
    }

    // ---- Whb store: col = lm = t, rows v = vb + kg*4 + r ----
    #pragma unroll
    for (int wi = 0; wi < 8; ++wi) {
        int p = h*W_ + wc*8 + wi;
        unsigned short u0 = bf16bits(acc[wi][0]);
        unsigned short u1 = bf16bits(acc[wi][1]);
        unsigned short u2 = bf16bits(acc[wi][2]);
        unsigned short u3 = bf16bits(acc[wi][3]);
        uint2 pk;
        pk.x = (unsigned)u0 | ((unsigned)u1 << 16);
        pk.y = (unsigned)u2 | ((unsigned)u3 << 16);
        *(uint2*)(Whb + ((size_t)(b*T_ + lm)*P_ + p)*V_ + vb + kg*4) = pk;
    }

    __syncthreads();
    if (tid < 16) {
        float a = sEi[0][tid] + sEi[1][tid] + sEi[2][tid] + sEi[3][tid];
        float c = sEj[0][tid] + sEj[1][tid] + sEj[2][tid] + sEj[3][tid];
        Eihi[((size_t)b*H_ + h)*V_ + vb + tid] = a;
        Eihj[((size_t)b*H_ + h)*V_ + vb + tid] = c;
    }
}

// ---------------------------------------------------------------------------
// Kernel 2: att + Mt, with self-computed adj_norm (d12 factored out).
// grid = N*V (1024), one (b,j) per block, block 256.
// M[b,j,t,v] = sum_i att[i,t]*rownorm[i][v]*d[i]*d[v]
//            = d[v] * sum_i (att[i,t]*d[i]) * rownorm[i][v]
// Mt[b][t][v][j] bf16 (B-operand layout for out_k MFMA).
// ---------------------------------------------------------------------------
__global__ __launch_bounds__(256) void att_m_k(const float* __restrict__ Eihi,
                                               const float* __restrict__ Eihj,
                                               const float* __restrict__ Bm,
                                               __hip_bfloat16* __restrict__ Mt) {
    int b = blockIdx.x >> 6;
    int j = blockIdx.x & 63;
    int tid = threadIdx.x;
    __shared__ float sadj[64][65];   // rownorm (padded)
    __shared__ float s_att[64][17];  // att[i][t] * d[i] (padded)
    __shared__ float sd[64];

    if (tid < 64) {
        int i = tid;
        // coalesced Bm -> LDS
        for (int r = 0; r < 64; ++r) sadj[r][i] = Bm[r*64 + i];
        // row min/max (+identity), global reduce across the wave
        float mn = 1e30f, mx = -1e30f;
        #pragma unroll
        for (int v = 0; v < 64; ++v) {
            float x = sadj[i][v] + (v == i ? 1.f : 0.f);
            mn = fminf(mn, x);
            mx = fmaxf(mx, x);
        }
        #pragma unroll
        for (int off = 32; off > 0; off >>= 1) {
            mn = fminf(mn, __shfl_xor(mn, off));
            mx = fmaxf(mx, __shfl_xor(mx, off));
        }
        float inv = 1.f / (mx - mn);
        float rs = 0.f;
        #pragma unroll
        for (int v = 0; v < 64; ++v) {
            float x = (sadj[i][v] + (v == i ? 1.f : 0.f) - mn) * inv;
            rs += x;
            sadj[i][v] = x;
        }
        float d = rsqrtf(rs);
        sd[i] = d;

        // softmax over t for this (i, j)
        const float* ebi = Eihi + (size_t)b*H_*V_;
        const float* ebj = Eihj + (size_t)b*H_*V_;
        float ev[16];
        float mxe = -1e30f;
        #pragma unroll
        for (int t = 0; t < 16; ++t) {
            float x = ebi[(2*t)*V_ + i] + ebi[(2*t+1)*V_ + i]
                    + ebj[(2*t)*V_ + j] + ebj[(2*t+1)*V_ + j];
            x = (x >= 0.f) ? x : ALPHA_ * x;
            ev[t] = x;
            mxe = fmaxf(mxe, x);
        }
        float s = 0.f;
        #pragma unroll
        for (int t = 0; t < 16; ++t) {
            ev[t] = __expf(ev[t] - mxe);
            s += ev[t];
        }
        float invs = d / s;   // fold d[i] into att row
        #pragma unroll
        for (int t = 0; t < 16; ++t) s_att[i][t] = ev[t] * invs;
    }
    __syncthreads();

    int v = tid & 63, tq = tid >> 6;
    float acc[4] = {0.f, 0.f, 0.f, 0.f};
    for (int i = 0; i < 64; ++i) {
        float an = sadj[i][v];
        #pragma unroll
        for (int u = 0; u < 4; ++u) acc[u] += s_att[i][tq*4 + u] * an;
    }
    float dv = sd[v];
    #pragma unroll
    for (int u = 0; u < 4; ++u) {
        int t = tq*4 + u;
        Mt[(((size_t)b*T_ + t)*V_ + v)*V_ + j] = __float2bfloat16(acc[u] * dv);
    }
}

// ---------------------------------------------------------------------------
// Kernel 3 (MFMA): out[b,p,t,v] = elu( sum_j Whb[b,t,p,j] * Mt[b,t,v,j] ).
// ---------------------------------------------------------------------------
__global__ __launch_bounds__(256) void out_k(const __hip_bfloat16* __restrict__ Whb,
                                             const __hip_bfloat16* __restrict__ Mt,
                                             float* __restrict__ out) {
    int bi = blockIdx.x;
    int pc = bi & 7;
    int t  = (bi >> 3) & 15;
    int b  = bi >> 7;

    int tid  = threadIdx.x;
    int lane = tid & 63;
    int wid  = tid >> 6;
    int lm   = lane & 15;
    int lk   = lane >> 4;

    const __hip_bfloat16* Ab = Whb + ((size_t)(b*T_ + t)*P_ + pc*128) * V_;
    const __hip_bfloat16* Bb = Mt  + (size_t)(b*T_ + t) * (V_*V_);

    f32x4 acc[2][4];
    #pragma unroll
    for (int pt = 0; pt < 2; ++pt)
        #pragma unroll
        for (int vt = 0; vt < 4; ++vt) acc[pt][vt] = (f32x4){0.f,0.f,0.f,0.f};

    #pragma unroll
    for (int kf = 0; kf < 2; ++kf) {
        int ko = kf*32 + lk*8;
        bf16x8 a0 = *(const bf16x8*)(Ab + ((size_t)((wid*2+0)*16 + lm))*V_ + ko);
        bf16x8 a1 = *(const bf16x8*)(Ab + ((size_t)((wid*2+1)*16 + lm))*V_ + ko);
        #pragma unroll
        for (int vt = 0; vt < 4; ++vt) {
            bf16x8 bf = *(const bf16x8*)(Bb + ((size_t)(vt*16 + lm))*V_ + ko);
            acc[0][vt] = __builtin_amdgcn_mfma_f32_16x16x32_bf16(a0, bf, acc[0][vt], 0, 0, 0);
            acc[1][vt] = __builtin_amdgcn_mfma_f32_16x16x32_bf16(a1, bf, acc[1][vt], 0, 0, 0);
        }
    }

    #pragma unroll
    for (int pt = 0; pt < 2; ++pt) {
        #pragma unroll
        for (int vt = 0; vt < 4; ++vt) {
            #pragma unroll
            for (int r = 0; r < 4; ++r) {
                int p  = pc*128 + (wid*2 + pt)*16 + lk*4 + r;
                int vv = vt*16 + lm;
                float x = acc[pt][vt][r];
                x = (x > 0.f) ? x : (__expf(x) - 1.f);
                out[((size_t)(b*P_ + p)*T_ + t)*V_ + vv] = x;
            }
        }
    }
}

// ---------------------------------------------------------------------------
extern "C" void kernel_launch(void* const* d_in, const int* in_sizes, int n_in,
                              void* d_out, int out_size, void* d_ws, size_t ws_size,
                              hipStream_t stream) {
    const float* X  = (const float*)d_in[0];  // h: (16,32,32,16,64)
    const float* CW = (const float*)d_in[1];  // conv_w: (3,3,16,16)
    const float* CB = (const float*)d_in[2];  // conv_b: (16,)
    const float* av = (const float*)d_in[3];  // a: (2048,1)
    const float* Bm = (const float*)d_in[4];  // B: (64,64)
    float* outp = (float*)d_out;

    // ws: Whb (33.55MB) | Mt (2MB) | Eihi | Eihj
    __hip_bfloat16* Whb = (__hip_bfloat16*)d_ws;
    __hip_bfloat16* Mt  = Whb + (size_t)N_*T_*P_*V_;
    float* Eihi = (float*)(Mt + (size_t)N_*T_*V_*V_);   // 16*32*64
    float* Eihj = Eihi + (size_t)N_*H_*V_;

    conv_k <<<2048,    256, 0, stream>>>(X, CW, CB, av, Whb, Eihi, Eihj);
    att_m_k<<<N_*V_,   256, 0, stream>>>(Eihi, Eihj, Bm, Mt);
    out_k  <<<N_*T_*8, 256, 0, stream>>>(Whb, Mt, outp);
}

// Round 7
// 78.587 us; speedup vs baseline: 1.0500x; 1.0500x over previous
//
#include <hip/hip_runtime.h>
#include <hip/hip_bf16.h>
#include <math.h>

#define ALPHA_ 0.2f
#define N_ 16
#define H_ 32
#define W_ 32
#define T_ 16
#define V_ 64
#define P_ (H_*W_)  // 1024

typedef __bf16 bf16x8 __attribute__((ext_vector_type(8)));
typedef float  f32x4  __attribute__((ext_vector_type(4)));

static __device__ inline bf16x8 zero8() {
    bf16x8 z;
    #pragma unroll
    for (int i = 0; i < 8; ++i) z[i] = (__bf16)0.f;
    return z;
}

static __device__ inline unsigned short bf16bits(float f) {
    __hip_bfloat16 b = __float2bfloat16(f);
    return *reinterpret_cast<unsigned short*>(&b);
}

static __device__ inline __bf16 tobf(float f) {
    unsigned short u = bf16bits(f);
    return *reinterpret_cast<__bf16*>(&u);
}

// ---------------------------------------------------------------------------
// Kernel 1: fused transpose + conv MFMA + Ei/Ej partials.
// grid = 2048 (XCD-grouped), bi -> (b, h, vg). block 256 = 4 waves (w-chunks).
// LDS tile: seg = (r*32+w)*2+th blocks of 256B; within a block, v-granule
// (16B = 8 ti bf16) stored at swizzled index g' = v ^ th ^ ((w&1)<<1).
// -> ds_write banks: {tpl, k2b0^th, k2b1^(w&1), v4i&1} = 32 distinct (free);
// -> ds_read_b128: per-16-lane permuted 256B block (free); XOR is a
//    compile-time constant per u (two precomputed bases).
// Staging: burst-load 24 f32x4 into regs, then convert+write (MLP).
// k-map: dh = kg>>1 (f01) / 2 (f2), ti = (kg&1)*8 + i  [same as prior rounds].
// Whb stored bf16 as (b, t, p, v); Eih*[b][h][v] partials from fp32 acc.
// ---------------------------------------------------------------------------
__global__ __launch_bounds__(256, 2) void conv_k(const float* __restrict__ X,
                                                 const float* __restrict__ CW,
                                                 const float* __restrict__ CB,
                                                 const float* __restrict__ av,
                                                 __hip_bfloat16* __restrict__ Whb,
                                                 float* __restrict__ Eihi,
                                                 float* __restrict__ Eihj) {
    __shared__ __align__(16) __hip_bfloat16 sx[3*32*2*16*8];  // 49152 B
    __shared__ float sEi[4][16], sEj[4][16];

    int orig = blockIdx.x;
    int bi   = (orig & 7) * 256 + (orig >> 3);   // 8 XCDs x 256 contiguous
    int b    = bi >> 7;
    int rem  = bi & 127;
    int h    = rem >> 2;
    int vg   = rem & 3, vb = vg * 16;

    int tid = threadIdx.x, lane = tid & 63, wc = tid >> 6;
    int lm = lane & 15, kg = lane >> 4;

    // ---- self-computed B fragments ----
    bf16x8 Bf01[3], Bf2[3];
    #pragma unroll
    for (int dw = 0; dw < 3; ++dw) {
        #pragma unroll
        for (int i = 0; i < 8; ++i) {
            int ti = (kg & 1)*8 + i;
            int dh = kg >> 1;
            Bf01[dw][i] = tobf(CW[((dh*3+dw)*16+ti)*16 + lm]);
            Bf2 [dw][i] = (kg < 2) ? tobf(CW[((6+dw)*16+ti)*16 + lm]) : (__bf16)0.f;
        }
    }
    float cb = CB[lm];
    f32x4 acc[8];
    #pragma unroll
    for (int wi = 0; wi < 8; ++wi) acc[wi] = (f32x4){cb, cb, cb, cb};

    // ---- stage X slab -> LDS (burst loads, swizzled conflict-free writes) --
    unsigned* sxw = (unsigned*)sx;
    int v4i = tid & 3, tiP = (tid >> 2) & 7, sub = tid >> 5;   // sub 0..7
    int th  = tiP >> 2, tpl = tiP & 3;
    const float* Xbase = X + (size_t)b*(H_*W_*T_*V_) + (size_t)(2*tiP)*V_ + vb + v4i*4;

    f32x4 xa[12], xb[12];
    #pragma unroll
    for (int it = 0; it < 12; ++it) {
        int rest = it*8 + sub;        // 0..95 = r*32 + w
        int w = rest & 31, r = rest >> 5;
        int hy = h - 1 + r;
        xa[it] = (f32x4){0.f,0.f,0.f,0.f};
        xb[it] = (f32x4){0.f,0.f,0.f,0.f};
        if ((unsigned)hy < (unsigned)H_) {
            const float* p = Xbase + ((size_t)hy*W_ + w)*(T_*V_);
            xa[it] = *(const f32x4*)(p);
            xb[it] = *(const f32x4*)(p + V_);
        }
    }
    #pragma unroll
    for (int it = 0; it < 12; ++it) {
        int rest = it*8 + sub;
        int w = rest & 31, r = rest >> 5;
        int seg = (r*32 + w)*2 + th;
        int swz = th ^ ((w & 1) << 1);
        #pragma unroll
        for (int k2 = 0; k2 < 4; ++k2) {
            int gs = (v4i*4 + k2) ^ swz;      // swizzled v-granule
            unsigned pk = (unsigned)bf16bits(xa[it][k2])
                        | ((unsigned)bf16bits(xb[it][k2]) << 16);
            sxw[seg*64 + gs*4 + tpl] = pk;
        }
    }
    __syncthreads();

    // ---- MFMA u-loop (A-frags from LDS, swizzle folded into 2 bases) ----
    const char* sxb = (const char*)sx;
    int lmx  = (lm ^ (kg & 1)) * 16;
    int o01A = (kg>>1)*16384 + (kg&1)*256 + lmx;   // for wxu even
    int o01B = o01A ^ 32;                          // wxu odd (granule bit1)
    int o2A  = 2*16384 + (kg&1)*256 + lmx;
    int o2B  = o2A ^ 32;

    #pragma unroll
    for (int u = 0; u < 10; ++u) {
        int wxu = wc*8 + u - 1;
        const int oddw = (u + 1) & 1;              // == wxu & 1
        bf16x8 f01 = zero8(), f2 = zero8();
        if ((unsigned)wxu < (unsigned)W_) {        // wave-uniform edge test
            f01 = *(const bf16x8*)(sxb + (oddw ? o01B : o01A) + wxu*512);
            f2  = *(const bf16x8*)(sxb + (oddw ? o2B  : o2A ) + wxu*512);
        }
        #pragma unroll
        for (int dw = 0; dw < 3; ++dw) {
            int wi = u - dw;                       // compile-time
            if (wi >= 0 && wi < 8) {
                acc[wi] = __builtin_amdgcn_mfma_f32_16x16x32_bf16(f01, Bf01[dw], acc[wi], 0, 0, 0);
                acc[wi] = __builtin_amdgcn_mfma_f32_16x16x32_bf16(f2,  Bf2 [dw], acc[wi], 0, 0, 0);
            }
        }
    }

    // ---- fused Ei/Ej partials (lane holds t=lm, v=vb+kg*4+r) ----
    float si[4] = {0.f,0.f,0.f,0.f}, sj[4] = {0.f,0.f,0.f,0.f};
    {
        const float* avb = av + (h & 1)*1024 + wc*8*16 + lm;
        #pragma unroll
        for (int wi = 0; wi < 8; ++wi) {
            float ai = avb[wi*16];
            float aj = avb[wi*16 + 512];
            #pragma unroll
            for (int r = 0; r < 4; ++r) {
                si[r] += acc[wi][r] * ai;
                sj[r] += acc[wi][r] * aj;
            }
        }
        #pragma unroll
        for (int off = 1; off < 16; off <<= 1) {
            #pragma unroll
            for (int r = 0; r < 4; ++r) {
                si[r] += __shfl_xor(si[r], off);
                sj[r] += __shfl_xor(sj[r], off);
            }
        }
    }
    if (lm == 0) {
        #pragma unroll
        for (int r = 0; r < 4; ++r) {
            sEi[wc][kg*4 + r] = si[r];
            sEj[wc][kg*4 + r] = sj[r];
        }
    }

    // ---- Whb store: col = lm = t, rows v = vb + kg*4 + r ----
    #pragma unroll
    for (int wi = 0; wi < 8; ++wi) {
        int p = h*W_ + wc*8 + wi;
        unsigned short u0 = bf16bits(acc[wi][0]);
        unsigned short u1 = bf16bits(acc[wi][1]);
        unsigned short u2 = bf16bits(acc[wi][2]);
        unsigned short u3 = bf16bits(acc[wi][3]);
        uint2 pk;
        pk.x = (unsigned)u0 | ((unsigned)u1 << 16);
        pk.y = (unsigned)u2 | ((unsigned)u3 << 16);
        *(uint2*)(Whb + ((size_t)(b*T_ + lm)*P_ + p)*V_ + vb + kg*4) = pk;
    }

    __syncthreads();
    if (tid < 16) {
        float a = sEi[0][tid] + sEi[1][tid] + sEi[2][tid] + sEi[3][tid];
        float c = sEj[0][tid] + sEj[1][tid] + sEj[2][tid] + sEj[3][tid];
        Eihi[((size_t)b*H_ + h)*V_ + vb + tid] = a;
        Eihj[((size_t)b*H_ + h)*V_ + vb + tid] = c;
    }
}

// ---------------------------------------------------------------------------
// Kernel 2: att + Mt, with self-computed adj_norm (d12 factored out).
// grid = N*V (1024), one (b,j) per block, block 256.
// ---------------------------------------------------------------------------
__global__ __launch_bounds__(256) void att_m_k(const float* __restrict__ Eihi,
                                               const float* __restrict__ Eihj,
                                               const float* __restrict__ Bm,
                                               __hip_bfloat16* __restrict__ Mt) {
    int b = blockIdx.x >> 6;
    int j = blockIdx.x & 63;
    int tid = threadIdx.x;
    __shared__ float sadj[64][65];   // rownorm (padded)
    __shared__ float s_att[64][17];  // att[i][t] * d[i] (padded)
    __shared__ float sd[64];

    if (tid < 64) {
        int i = tid;
        for (int r = 0; r < 64; ++r) sadj[r][i] = Bm[r*64 + i];
        float mn = 1e30f, mx = -1e30f;
        #pragma unroll
        for (int v = 0; v < 64; ++v) {
            float x = sadj[i][v] + (v == i ? 1.f : 0.f);
            mn = fminf(mn, x);
            mx = fmaxf(mx, x);
        }
        #pragma unroll
        for (int off = 32; off > 0; off >>= 1) {
            mn = fminf(mn, __shfl_xor(mn, off));
            mx = fmaxf(mx, __shfl_xor(mx, off));
        }
        float inv = 1.f / (mx - mn);
        float rs = 0.f;
        #pragma unroll
        for (int v = 0; v < 64; ++v) {
            float x = (sadj[i][v] + (v == i ? 1.f : 0.f) - mn) * inv;
            rs += x;
            sadj[i][v] = x;
        }
        float d = rsqrtf(rs);
        sd[i] = d;

        const float* ebi = Eihi + (size_t)b*H_*V_;
        const float* ebj = Eihj + (size_t)b*H_*V_;
        float ev[16];
        float mxe = -1e30f;
        #pragma unroll
        for (int t = 0; t < 16; ++t) {
            float x = ebi[(2*t)*V_ + i] + ebi[(2*t+1)*V_ + i]
                    + ebj[(2*t)*V_ + j] + ebj[(2*t+1)*V_ + j];
            x = (x >= 0.f) ? x : ALPHA_ * x;
            ev[t] = x;
            mxe = fmaxf(mxe, x);
        }
        float s = 0.f;
        #pragma unroll
        for (int t = 0; t < 16; ++t) {
            ev[t] = __expf(ev[t] - mxe);
            s += ev[t];
        }
        float invs = d / s;   // fold d[i] into att row
        #pragma unroll
        for (int t = 0; t < 16; ++t) s_att[i][t] = ev[t] * invs;
    }
    __syncthreads();

    int v = tid & 63, tq = tid >> 6;
    float acc[4] = {0.f, 0.f, 0.f, 0.f};
    for (int i = 0; i < 64; ++i) {
        float an = sadj[i][v];
        #pragma unroll
        for (int u = 0; u < 4; ++u) acc[u] += s_att[i][tq*4 + u] * an;
    }
    float dv = sd[v];
    #pragma unroll
    for (int u = 0; u < 4; ++u) {
        int t = tq*4 + u;
        Mt[(((size_t)b*T_ + t)*V_ + v)*V_ + j] = __float2bfloat16(acc[u] * dv);
    }
}

// ---------------------------------------------------------------------------
// Kernel 3 (MFMA): out[b,p,t,v] = elu( sum_j Whb[b,t,p,j] * Mt[b,t,v,j] ).
// ---------------------------------------------------------------------------
__global__ __launch_bounds__(256) void out_k(const __hip_bfloat16* __restrict__ Whb,
                                             const __hip_bfloat16* __restrict__ Mt,
                                             float* __restrict__ out) {
    int bi = blockIdx.x;
    int pc = bi & 7;
    int t  = (bi >> 3) & 15;
    int b  = bi >> 7;

    int tid  = threadIdx.x;
    int lane = tid & 63;
    int wid  = tid >> 6;
    int lm   = lane & 15;
    int lk   = lane >> 4;

    const __hip_bfloat16* Ab = Whb + ((size_t)(b*T_ + t)*P_ + pc*128) * V_;
    const __hip_bfloat16* Bb = Mt  + (size_t)(b*T_ + t) * (V_*V_);

    f32x4 acc[2][4];
    #pragma unroll
    for (int pt = 0; pt < 2; ++pt)
        #pragma unroll
        for (int vt = 0; vt < 4; ++vt) acc[pt][vt] = (f32x4){0.f,0.f,0.f,0.f};

    #pragma unroll
    for (int kf = 0; kf < 2; ++kf) {
        int ko = kf*32 + lk*8;
        bf16x8 a0 = *(const bf16x8*)(Ab + ((size_t)((wid*2+0)*16 + lm))*V_ + ko);
        bf16x8 a1 = *(const bf16x8*)(Ab + ((size_t)((wid*2+1)*16 + lm))*V_ + ko);
        #pragma unroll
        for (int vt = 0; vt < 4; ++vt) {
            bf16x8 bf = *(const bf16x8*)(Bb + ((size_t)(vt*16 + lm))*V_ + ko);
            acc[0][vt] = __builtin_amdgcn_mfma_f32_16x16x32_bf16(a0, bf, acc[0][vt], 0, 0, 0);
            acc[1][vt] = __builtin_amdgcn_mfma_f32_16x16x32_bf16(a1, bf, acc[1][vt], 0, 0, 0);
        }
    }

    #pragma unroll
    for (int pt = 0; pt < 2; ++pt) {
        #pragma unroll
        for (int vt = 0; vt < 4; ++vt) {
            #pragma unroll
            for (int r = 0; r < 4; ++r) {
                int p  = pc*128 + (wid*2 + pt)*16 + lk*4 + r;
                int vv = vt*16 + lm;
                float x = acc[pt][vt][r];
                x = (x > 0.f) ? x : (__expf(x) - 1.f);
                out[((size_t)(b*P_ + p)*T_ + t)*V_ + vv] = x;
            }
        }
    }
}

// ---------------------------------------------------------------------------
extern "C" void kernel_launch(void* const* d_in, const int* in_sizes, int n_in,
                              void* d_out, int out_size, void* d_ws, size_t ws_size,
                              hipStream_t stream) {
    const float* X  = (const float*)d_in[0];  // h: (16,32,32,16,64)
    const float* CW = (const float*)d_in[1];  // conv_w: (3,3,16,16)
    const float* CB = (const float*)d_in[2];  // conv_b: (16,)
    const float* av = (const float*)d_in[3];  // a: (2048,1)
    const float* Bm = (const float*)d_in[4];  // B: (64,64)
    float* outp = (float*)d_out;

    // ws: Whb (33.55MB) | Mt (2MB) | Eihi | Eihj
    __hip_bfloat16* Whb = (__hip_bfloat16*)d_ws;
    __hip_bfloat16* Mt  = Whb + (size_t)N_*T_*P_*V_;
    float* Eihi = (float*)(Mt + (size_t)N_*T_*V_*V_);   // 16*32*64
    float* Eihj = Eihi + (size_t)N_*H_*V_;

    conv_k <<<2048,    256, 0, stream>>>(X, CW, CB, av, Whb, Eihi, Eihj);
    att_m_k<<<N_*V_,   256, 0, stream>>>(Eihi, Eihj, Bm, Mt);
    out_k  <<<N_*T_*8, 256, 0, stream>>>(Whb, Mt, outp);
}